// Round 10
// baseline (560.775 us; speedup 1.0000x reference)
//
#include <hip/hip_runtime.h>
#include <stdint.h>

#define NNODES 50000
#define NEDGES 800000
#define CDIM   64
#define SHD    9
#define EBD    16

using f32x4  = __attribute__((ext_vector_type(4))) float;
using bf16x8 = __attribute__((ext_vector_type(8))) __bf16;

static __device__ __forceinline__ unsigned short bfr(float x) {
  union { __bf16 b; unsigned short u; } t;
  t.b = (__bf16)x;            // native cvt, RNE (compiler packs into v_cvt_pk_bf16_f32)
  return t.u;
}
static __device__ __forceinline__ float bf2f(unsigned short b) {
  union { unsigned u; float f; } v; v.u = ((unsigned)b) << 16;
  return v.f;
}
static __device__ __forceinline__ f32x4 mfma16(bf16x8 a, bf16x8 b, f32x4 c) {
  return __builtin_amdgcn_mfma_f32_16x16x32_bf16(a, b, c, 0, 0, 0);
}
static __device__ __forceinline__ ushort4 cvt4(float4 v) {
  return make_ushort4(bfr(v.x), bfr(v.y), bfr(v.z), bfr(v.w));
}
static __device__ __forceinline__ bf16x8 pack8(float4 a, float4 b) {
  union { unsigned short u[8]; bf16x8 v; } t;
  t.u[0]=bfr(a.x); t.u[1]=bfr(a.y); t.u[2]=bfr(a.z); t.u[3]=bfr(a.w);
  t.u[4]=bfr(b.x); t.u[5]=bfr(b.y); t.u[6]=bfr(b.z); t.u[7]=bfr(b.w);
  return t.v;
}

// fp32 w[K][N] row-major -> bf16 B-fragment order for mfma_f32_16x16x32_bf16:
// dst[((nt*KS+ks)*64 + lane)*8 + j] = w[ks*32+(lane>>4)*8+j][nt*16+(lane&15)], 0-padded.
__global__ void pack_all_kernel(
    const float* __restrict__ wev1, const float* __restrict__ weu1,
    const float* __restrict__ wnl1, const float* __restrict__ weu2,
    const float* __restrict__ wnl2, const float* __restrict__ wev2,
    const float* __restrict__ wtp,
    unsigned short* __restrict__ pev1, unsigned short* __restrict__ peu1,
    unsigned short* __restrict__ pnl1, unsigned short* __restrict__ peu2,
    unsigned short* __restrict__ pnl2, unsigned short* __restrict__ pev2,
    unsigned short* __restrict__ ptp) {
  int b = blockIdx.x;
  const float* w; unsigned short* dst; int K, N, KS, NT, base;
  if (b < 24)      { w = wev1; dst = pev1; K = 192; N = 256; KS = 6; NT = 16; base = 0; }
  else if (b < 48) { w = weu1; dst = peu1; K = 192; N = 256; KS = 6; NT = 16; base = 24; }
  else if (b < 64) { w = wnl1; dst = pnl1; K = 128; N = 256; KS = 4; NT = 16; base = 48; }
  else if (b < 72) { w = weu2; dst = peu2; K = 256; N = 64;  KS = 8; NT = 4;  base = 64; }
  else if (b < 80) { w = wnl2; dst = pnl2; K = 256; N = 64;  KS = 8; NT = 4;  base = 72; }
  else if (b < 82) { w = wev2; dst = pev2; K = 256; N = 9;   KS = 8; NT = 1;  base = 80; }
  else             { w = wtp;  dst = ptp;  K = 34;  N = 64;  KS = 2; NT = 4;  base = 82; }
  int idx = (b - base) * 256 + threadIdx.x;
  int total = NT * KS * 64;
  if (idx >= total) return;
  int lane = idx & 63;
  int t = idx >> 6;
  int ks = t % KS;
  int nt = t / KS;
  int n  = nt * 16 + (lane & 15);
  int kb = ks * 32 + ((lane >> 4) << 3);
  unsigned short v[8];
#pragma unroll
  for (int j = 0; j < 8; ++j) {
    int k = kb + j;
    float val = (k < K && n < N) ? w[(size_t)k * N + n] : 0.f;
    v[j] = bfr(val);
  }
  uint4 pk;
  pk.x = (unsigned)v[0] | ((unsigned)v[1] << 16);
  pk.y = (unsigned)v[2] | ((unsigned)v[3] << 16);
  pk.z = (unsigned)v[4] | ((unsigned)v[5] << 16);
  pk.w = (unsigned)v[6] | ((unsigned)v[7] << 16);
  reinterpret_cast<uint4*>(dst)[idx] = pk;
}

// R2 structure, LDS diet: he lives in registers/global (not LDS); vt overlays act.
// 64 edges/block, 4 waves, 34,816 B LDS -> 4 blocks/CU (16 waves/CU).
__global__ __launch_bounds__(256, 4) void edge_kernel(
    const float* __restrict__ hn, const float* __restrict__ he,
    const float* __restrict__ fe, const float* __restrict__ fes,
    const float* __restrict__ nrm,
    const int* __restrict__ esrc, const int* __restrict__ edst,
    const unsigned short* __restrict__ pev1, const float* __restrict__ bev1,
    const unsigned short* __restrict__ pev2, const float* __restrict__ bev2,
    const unsigned short* __restrict__ ptp,  const float* __restrict__ btp,
    const unsigned short* __restrict__ peu1, const float* __restrict__ beu1,
    const unsigned short* __restrict__ peu2, const float* __restrict__ beu2,
    float* __restrict__ out_he, float* __restrict__ nf) {
  __shared__ unsigned short xa[64][136];   // [hs | hd] bf16 (stride 68 dw === 4 mod 32)
  __shared__ unsigned short av[64][136];   // act half; later overlaid vt ([v|fe|fes|0] then t)

  const int tid  = threadIdx.x;
  const int lane = tid & 63;
  const int wid  = tid >> 6;
  const int eb   = blockIdx.x * 64;
  const int arow = lane & 15;
  const int jj   = lane >> 4;
  const int koff = jj << 3;
  const int r0   = jj << 2;

  // ---- stage hs|hd into LDS (thread t -> edge t>>2, quarter t&3) ----
  {
    const int e  = tid >> 2;
    const int q  = tid & 3;
    const int cg = q << 4;
    const int eg = eb + e;
    const int src = esrc[eg];
    const int dst = edst[eg];
    const float4* hsP = reinterpret_cast<const float4*>(hn + (size_t)src * 64 + cg);
    const float4* hdP = reinterpret_cast<const float4*>(hn + (size_t)dst * 64 + cg);
#pragma unroll
    for (int i = 0; i < 4; ++i) {
      *reinterpret_cast<ushort4*>(&xa[e][cg + i * 4])      = cvt4(hsP[i]);
      *reinterpret_cast<ushort4*>(&xa[e][64 + cg + i * 4]) = cvt4(hdP[i]);
    }
  }
  // ---- he A-frags into registers (per-wave, from global; coalesced 16-row reads) ----
  bf16x8 bhe[4][2];
#pragma unroll
  for (int m = 0; m < 4; ++m) {
    const float* hrow = he + (size_t)(eb + m * 16 + arow) * 64;
#pragma unroll
    for (int ks = 0; ks < 2; ++ks) {
      float4 p0 = *reinterpret_cast<const float4*>(hrow + ks * 32 + koff);
      float4 p1 = *reinterpret_cast<const float4*>(hrow + ks * 32 + koff + 4);
      bhe[m][ks] = pack8(p0, p1);
    }
  }
  __syncthreads();  // S1

  // ---- GEMM1 (two N-halves) interleaved with GEMM2 partial-K ----
  f32x4 acc2 = (f32x4){0.f, 0.f, 0.f, 0.f};
#pragma unroll
  for (int h = 0; h < 2; ++h) {
    {
      f32x4 acc[4][2];
#pragma unroll
      for (int m = 0; m < 4; ++m)
#pragma unroll
        for (int n = 0; n < 2; ++n) acc[m][n] = (f32x4){0.f, 0.f, 0.f, 0.f};
#pragma unroll
      for (int ks = 0; ks < 6; ++ks) {
        bf16x8 a[4];
#pragma unroll
        for (int m = 0; m < 4; ++m) {
          if (ks < 2) a[m] = bhe[m][ks];
          else        a[m] = *reinterpret_cast<const bf16x8*>(&xa[m * 16 + arow][(ks - 2) * 32 + koff]);
        }
#pragma unroll
        for (int n = 0; n < 2; ++n) {
          bf16x8 b = *reinterpret_cast<const bf16x8*>(
              pev1 + (((size_t)(h * 8 + wid * 2 + n) * 6 + ks) * 64 + lane) * 8);
#pragma unroll
          for (int m = 0; m < 4; ++m) acc[m][n] = mfma16(a[m], b, acc[m][n]);
        }
      }
#pragma unroll
      for (int n = 0; n < 2; ++n) {
        const int col_l = wid * 32 + n * 16 + arow;
        const float bias = bev1[h * 128 + col_l];
#pragma unroll
        for (int m = 0; m < 4; ++m)
#pragma unroll
          for (int r = 0; r < 4; ++r) {
            float v = acc[m][n][r] + bias;
            av[m * 16 + r0 + r][col_l] = bfr(v > 0.f ? v : 0.f);
          }
      }
    }
    __syncthreads();  // S2 / S4
    {
      const int mrow = wid * 16 + arow;
#pragma unroll
      for (int ksl = 0; ksl < 4; ++ksl) {
        bf16x8 a = *reinterpret_cast<const bf16x8*>(&av[mrow][ksl * 32 + koff]);
        bf16x8 b = *reinterpret_cast<const bf16x8*>(pev2 + (((size_t)h * 4 + ksl) * 64 + lane) * 8);
        acc2 = mfma16(a, b, acc2);
      }
    }
    if (h == 0) __syncthreads();  // S3
  }
  // All of this wave's GEMM2 reads of av rows [wid*16..wid*16+16) are done (in-wave
  // order); other waves' reads touch only their own rows. Safe to overlay vt now.

  // ---- overlay vt into av (own-wave rows): [v9|fe9|fes16|0...] cols 0..63 ----
  {
    const int e  = tid >> 2;       // row e belongs to wave e>>4 == wid
    const int q  = tid & 3;
    const int cg = q << 4;
    const int eg = eb + e;
#pragma unroll
    for (int i = 0; i < 16; ++i) {
      int col = cg + i;
      if (col < 9) continue;
      float v = 0.f;
      if (col < 18)      v = fe[(size_t)eg * SHD + (col - 9)];
      else if (col < 34) v = fes[(size_t)eg * EBD + (col - 18)];
      av[e][col] = bfr(v);
    }
  }
  if (arow < 9) {
    const float bias = bev2[arow];
#pragma unroll
    for (int r = 0; r < 4; ++r) av[wid * 16 + r0 + r][arow] = bfr(acc2[r] + bias);
  }
  // ---- GEMM_t (within-wave): t = [v|fe|fes] @ w_tp + b; overwrite own rows ----
  {
    f32x4 acct[4];
#pragma unroll
    for (int n = 0; n < 4; ++n) acct[n] = (f32x4){0.f, 0.f, 0.f, 0.f};
    const int mrow = wid * 16 + arow;
#pragma unroll
    for (int ks = 0; ks < 2; ++ks) {
      bf16x8 a = *reinterpret_cast<const bf16x8*>(&av[mrow][ks * 32 + koff]);
#pragma unroll
      for (int n = 0; n < 4; ++n) {
        bf16x8 b = *reinterpret_cast<const bf16x8*>(ptp + (((size_t)n * 2 + ks) * 64 + lane) * 8);
        acct[n] = mfma16(a, b, acct[n]);
      }
    }
#pragma unroll
    for (int n = 0; n < 4; ++n) {
      const int col = n * 16 + arow;
      const float bias = btp[col];
#pragma unroll
      for (int r = 0; r < 4; ++r) av[wid * 16 + r0 + r][col] = bfr(acct[n][r] + bias);
    }
  }
  __syncthreads();  // S5: t visible cross-wave

  // ---- hoist t A-frags to registers (reuses bhe storage pressure window) ----
  bf16x8 bt[4][2];
#pragma unroll
  for (int m = 0; m < 4; ++m) {
    bt[m][0] = *reinterpret_cast<const bf16x8*>(&av[m * 16 + arow][koff]);
    bt[m][1] = *reinterpret_cast<const bf16x8*>(&av[m * 16 + arow][32 + koff]);
  }
  __syncthreads();  // S6: all hoists done before GEMM3 overwrites av

  // ---- GEMM3 (two N-halves) interleaved with GEMM4 partial-K ----
  f32x4 acc4[4];
#pragma unroll
  for (int n = 0; n < 4; ++n) acc4[n] = (f32x4){0.f, 0.f, 0.f, 0.f};
#pragma unroll
  for (int h = 0; h < 2; ++h) {
    {
      f32x4 acc[4][2];
#pragma unroll
      for (int m = 0; m < 4; ++m)
#pragma unroll
        for (int n = 0; n < 2; ++n) acc[m][n] = (f32x4){0.f, 0.f, 0.f, 0.f};
#pragma unroll
      for (int ks = 0; ks < 6; ++ks) {
        bf16x8 a[4];
#pragma unroll
        for (int m = 0; m < 4; ++m) {
          if (ks < 2) a[m] = bt[m][ks];
          else        a[m] = *reinterpret_cast<const bf16x8*>(&xa[m * 16 + arow][(ks - 2) * 32 + koff]);
        }
#pragma unroll
        for (int n = 0; n < 2; ++n) {
          bf16x8 b = *reinterpret_cast<const bf16x8*>(
              peu1 + (((size_t)(h * 8 + wid * 2 + n) * 6 + ks) * 64 + lane) * 8);
#pragma unroll
          for (int m = 0; m < 4; ++m) acc[m][n] = mfma16(a[m], b, acc[m][n]);
        }
      }
#pragma unroll
      for (int n = 0; n < 2; ++n) {
        const int col_l = wid * 32 + n * 16 + arow;
        const float bias = beu1[h * 128 + col_l];
#pragma unroll
        for (int m = 0; m < 4; ++m)
#pragma unroll
          for (int r = 0; r < 4; ++r) {
            float v = acc[m][n][r] + bias;
            av[m * 16 + r0 + r][col_l] = bfr(v > 0.f ? v : 0.f);
          }
      }
    }
    __syncthreads();  // S7 / S9
    {
      const int mrow = wid * 16 + arow;
#pragma unroll
      for (int ksl = 0; ksl < 4; ++ksl) {
        bf16x8 a = *reinterpret_cast<const bf16x8*>(&av[mrow][ksl * 32 + koff]);
#pragma unroll
        for (int n = 0; n < 4; ++n) {
          bf16x8 b = *reinterpret_cast<const bf16x8*>(
              peu2 + (((size_t)(n * 8 + h * 4 + ksl)) * 64 + lane) * 8);
          acc4[n] = mfma16(a, b, acc4[n]);
        }
      }
    }
    if (h == 0) __syncthreads();  // S8
  }

  // ---- epilogue (R2-proven): he residual from global; coalesced stores + f32 atomics ----
#pragma unroll
  for (int r = 0; r < 4; ++r) {
    const int erow = wid * 16 + r0 + r;
    const int eg = eb + erow;
    const float nv = nrm[eg];
    const int dn = edst[eg];
    const float* herow = he + (size_t)eg * 64;
#pragma unroll
    for (int n = 0; n < 4; ++n) {
      const int col = n * 16 + arow;
      float v = acc4[n][r] + beu2[col] + herow[col];
      out_he[(size_t)eg * 64 + col] = v;
      atomicAdd(nf + (size_t)dn * 64 + col, v * nv);
    }
  }
}

// Node MLP (R2-proven): hn_new = hn + relu([hn|node_ftr]@w_nl1+b)@w_nl2+b
__global__ __launch_bounds__(256, 3) void node_kernel(
    const float* __restrict__ hn, const float* __restrict__ nf,
    const unsigned short* __restrict__ pnl1, const float* __restrict__ bnl1,
    const unsigned short* __restrict__ pnl2, const float* __restrict__ bnl2,
    float* __restrict__ out) {
  __shared__ unsigned short xn[64][136];
  __shared__ unsigned short act[64][264];
  const int tid = threadIdx.x, lane = tid & 63, wid = tid >> 6;
  const int nb = blockIdx.x * 64;
  const int arow = lane & 15, koff = (lane >> 4) << 3, r0 = (lane >> 4) << 2;
  {
    const int rrow = tid >> 2, q = tid & 3, cg = q << 4;
    const int g = nb + rrow;
    if (g < NNODES) {
      const float4* aP = reinterpret_cast<const float4*>(hn + (size_t)g * 64 + cg);
      const float4* bP = reinterpret_cast<const float4*>(nf + (size_t)g * 64 + cg);
#pragma unroll
      for (int i = 0; i < 4; ++i) {
        *reinterpret_cast<ushort4*>(&xn[rrow][cg + i * 4])      = cvt4(aP[i]);
        *reinterpret_cast<ushort4*>(&xn[rrow][64 + cg + i * 4]) = cvt4(bP[i]);
      }
    } else {
      ushort4 z = make_ushort4(0, 0, 0, 0);
#pragma unroll
      for (int i = 0; i < 4; ++i) {
        *reinterpret_cast<ushort4*>(&xn[rrow][cg + i * 4]) = z;
        *reinterpret_cast<ushort4*>(&xn[rrow][64 + cg + i * 4]) = z;
      }
    }
  }
  __syncthreads();
  {
    f32x4 acc[4][4];
#pragma unroll
    for (int m = 0; m < 4; ++m)
#pragma unroll
      for (int n = 0; n < 4; ++n) acc[m][n] = (f32x4){0.f, 0.f, 0.f, 0.f};
#pragma unroll
    for (int ks = 0; ks < 4; ++ks) {
      bf16x8 a[4];
#pragma unroll
      for (int m = 0; m < 4; ++m)
        a[m] = *reinterpret_cast<const bf16x8*>(&xn[m * 16 + arow][ks * 32 + koff]);
#pragma unroll
      for (int n = 0; n < 4; ++n) {
        bf16x8 b = *reinterpret_cast<const bf16x8*>(
            pnl1 + (((size_t)(wid * 4 + n) * 4 + ks) * 64 + lane) * 8);
#pragma unroll
        for (int m = 0; m < 4; ++m) acc[m][n] = mfma16(a[m], b, acc[m][n]);
      }
    }
#pragma unroll
    for (int n = 0; n < 4; ++n) {
      const int col = wid * 64 + n * 16 + arow;
      const float bias = bnl1[col];
#pragma unroll
      for (int m = 0; m < 4; ++m)
#pragma unroll
        for (int r = 0; r < 4; ++r) {
          float v = acc[m][n][r] + bias;
          act[m * 16 + r0 + r][col] = bfr(v > 0.f ? v : 0.f);
        }
    }
  }
  __syncthreads();
  {
    f32x4 acc[4];
#pragma unroll
    for (int n = 0; n < 4; ++n) acc[n] = (f32x4){0.f, 0.f, 0.f, 0.f};
    const int mrow = wid * 16 + arow;
#pragma unroll
    for (int ks = 0; ks < 8; ++ks) {
      bf16x8 a = *reinterpret_cast<const bf16x8*>(&act[mrow][ks * 32 + koff]);
#pragma unroll
      for (int n = 0; n < 4; ++n) {
        bf16x8 b = *reinterpret_cast<const bf16x8*>(pnl2 + (((size_t)n * 8 + ks) * 64 + lane) * 8);
        acc[n] = mfma16(a, b, acc[n]);
      }
    }
#pragma unroll
    for (int r = 0; r < 4; ++r) {
      const int row = wid * 16 + r0 + r;
      const int g = nb + row;
      if (g < NNODES) {
#pragma unroll
        for (int n = 0; n < 4; ++n) {
          const int col = n * 16 + arow;
          out[(size_t)g * 64 + col] = bf2f(xn[row][col]) + acc[n][r] + bnl2[col];
        }
      }
    }
  }
}

extern "C" void kernel_launch(void* const* d_in, const int* in_sizes, int n_in,
                              void* d_out, int out_size, void* d_ws, size_t ws_size,
                              hipStream_t stream) {
  const float* hn   = (const float*)d_in[0];
  const float* he   = (const float*)d_in[1];
  const float* fe   = (const float*)d_in[2];
  const float* fes  = (const float*)d_in[3];
  const float* nrm  = (const float*)d_in[4];
  const int*   esrc = (const int*)d_in[5];
  const int*   edst = (const int*)d_in[6];
  const float* w_ev1 = (const float*)d_in[7];  const float* b_ev1 = (const float*)d_in[8];
  const float* w_ev2 = (const float*)d_in[9];  const float* b_ev2 = (const float*)d_in[10];
  const float* w_tp  = (const float*)d_in[11]; const float* b_tp  = (const float*)d_in[12];
  const float* w_eu1 = (const float*)d_in[13]; const float* b_eu1 = (const float*)d_in[14];
  const float* w_eu2 = (const float*)d_in[15]; const float* b_eu2 = (const float*)d_in[16];
  const float* w_nl1 = (const float*)d_in[17]; const float* b_nl1 = (const float*)d_in[18];
  const float* w_nl2 = (const float*)d_in[19]; const float* b_nl2 = (const float*)d_in[20];

  float* out = (float*)d_out;
  char* ws = (char*)d_ws;
  float* nfp = (float*)ws;                                   // node_ftr accumulator [N,64] f32
  size_t off = (size_t)NNODES * CDIM * sizeof(float);
  unsigned short* pev1 = (unsigned short*)(ws + off); off += (size_t)16 * 6 * 512 * 2;
  unsigned short* peu1 = (unsigned short*)(ws + off); off += (size_t)16 * 6 * 512 * 2;
  unsigned short* pev2 = (unsigned short*)(ws + off); off += (size_t)1 * 8 * 512 * 2;
  unsigned short* peu2 = (unsigned short*)(ws + off); off += (size_t)4 * 8 * 512 * 2;
  unsigned short* ptp  = (unsigned short*)(ws + off); off += (size_t)4 * 2 * 512 * 2;
  unsigned short* pnl1 = (unsigned short*)(ws + off); off += (size_t)16 * 4 * 512 * 2;
  unsigned short* pnl2 = (unsigned short*)(ws + off); off += (size_t)4 * 8 * 512 * 2;

  hipMemsetAsync(nfp, 0, (size_t)NNODES * CDIM * sizeof(float), stream);

  pack_all_kernel<<<84, 256, 0, stream>>>(
      w_ev1, w_eu1, w_nl1, w_eu2, w_nl2, w_ev2, w_tp,
      pev1, peu1, pnl1, peu2, pnl2, pev2, ptp);

  edge_kernel<<<NEDGES / 64, 256, 0, stream>>>(
      hn, he, fe, fes, nrm, esrc, edst,
      pev1, b_ev1, pev2, b_ev2, ptp, b_tp, peu1, b_eu1, peu2, b_eu2,
      out + (size_t)NNODES * CDIM, nfp);

  node_kernel<<<(NNODES + 63) / 64, 256, 0, stream>>>(
      hn, nfp, pnl1, b_nl1, pnl2, b_nl2, out);
}